// Round 12
// baseline (1295.123 us; speedup 1.0000x reference)
//
#include <hip/hip_runtime.h>

#define NPADC 40
#define NZ 26
#define NXI 120            // interior nx (seismo width)
#define NZP 106
#define NXP 200
#define NCELL (NZP * NXP)

#define KSTEPS 5
#define HALO (2 * KSTEPS)          // 10
// z tiles: 6 of 11 + 4 of 10 (all >= HALO); x tiles: 20 of 10
#define NZB 10
#define NXB 20
#define NBLOCKS (NZB * NXB)        // 200
#define TXB 10                     // constant x tile size
#define EXT_XM (TXB + 2 * HALO)    // 30 (constant LDS row stride)
#define EZMAX (11 + 2 * HALO)      // 31
#define LDSN (EZMAX * EXT_XM)      // 930
#define NTHREADS 960               // 15 waves; one thread per ext-tile cell
#define FLAGSTRIDE 32              // uints -> 128 B per flag line

#define AGENT __HIP_MEMORY_SCOPE_AGENT

__device__ __forceinline__ float aload(float* p) {
    return __hip_atomic_load(p, __ATOMIC_RELAXED, AGENT);
}
__device__ __forceinline__ void astore(float* p, float v) {
    __hip_atomic_store(p, v, __ATOMIC_RELAXED, AGENT);
}

// ---- damp profile, matching _damp_profile in fp32 ----
__device__ __forceinline__ float dprof(int idx, int n) {
#pragma clang fp contract(off)
    float fi = (float)idx;
    float left = 1.0f, right = 1.0f;
    if (idx < NPADC) {
        float a = 0.015f * ((float)NPADC - fi);
        left = expf(-(a * a));
    }
    if (idx >= n - NPADC) {
        float a = 0.015f * (fi - (float)(n - NPADC - 1));
        right = expf(-(a * a));
    }
    return left * right;
}

// ---- one-time setup: coefficients into ws, init state buf0, zero flags ----
__global__ void setup_kernel(const float* __restrict__ vp,
                             const float* __restrict__ vs,
                             const float* __restrict__ den,
                             const float* __restrict__ ivec,
                             const float* __restrict__ temp,
                             float* __restrict__ coeff,
                             float* __restrict__ buf0,
                             unsigned* __restrict__ flags) {
#pragma clang fp contract(off)
    int i = blockIdx.x * blockDim.x + threadIdx.x;
    if (i < NBLOCKS * FLAGSTRIDE) flags[i] = 0u;
    if (i >= NCELL) return;
    int z = i / NXP;
    int x = i - z * NXP;

    float dtx = ivec[3];

    int zi = z - NPADC; zi = zi < 0 ? 0 : (zi > NZ - 1 ? NZ - 1 : zi);
    int xi = x - NPADC; xi = xi < 0 ? 0 : (xi > NXI - 1 ? NXI - 1 : xi);
    float vpv = vp[zi * NXI + xi];
    float vsv = vs[zi * NXI + xi];
    float d = den[i];

    float cav = (vpv * vpv) * d;     // ca
    float cmv = (vsv * vsv) * d;     // cm
    coeff[0 * NCELL + i] = dtx / d;                        // b
    coeff[1 * NCELL + i] = dprof(z, NZP) * dprof(x, NXP);  // damp
    coeff[2 * NCELL + i] = cav;                            // ca
    coeff[3 * NCELL + i] = cav - 2.0f * cmv;               // cl
    coeff[4 * NCELL + i] = dtx * cmv;                      // dtx*cm

    for (int f = 0; f < 5; ++f)
        buf0[f * NCELL + i] = temp[f * NCELL + i];
}

// lds field order: 0=vx 1=vz 2=txx 3=tzz 4=txz
// Invariant: for threads inside the current active region, the registers
// rvx,rvz,rtxx,rtzz,rtxz mirror lds[f][rc] bit-exactly.
__global__ __launch_bounds__(NTHREADS)
void persist_kernel(const float* __restrict__ coeff,
                    float* __restrict__ buf0, float* __restrict__ buf1,
                    const float* __restrict__ ivec, const float* __restrict__ s,
                    const int* __restrict__ iszp, const int* __restrict__ isxp,
                    float* __restrict__ fields_out,
                    float* __restrict__ illum_out,
                    float* __restrict__ seismo,
                    unsigned* __restrict__ flags,
                    int nt) {
#pragma clang fp contract(off)
    __shared__ float lds[5][LDSN];

    const int tid = threadIdx.x;
    const int bid = blockIdx.x;
    const int zb = bid / NXB, xb = bid - zb * NXB;
    const int z0  = (zb < 6) ? 11 * zb : 66 + (zb - 6) * 10;
    const int tzb = (zb < 6) ? 11 : 10;
    const int x0  = xb * TXB;
    const int ez  = tzb + 2 * HALO;                      // 31 or 30
    const int ncl = ez * EXT_XM;
    const float dt  = ivec[2];
    const float dtx = ivec[3];
    const int isz = *iszp, isx = *isxp;

    // ---- per-thread cell precompute (one cell per thread) ----
    const int rc = tid;
    const bool valid = rc < ncl;
    int izv = -1000, ixv = -1000, g = 0, seis = -1, ownerflag = 0;
    bool inter = false;
    float cb = 0.f, cd = 0.f, cca = 0.f, ccl = 0.f, cdtcm = 0.f;
    if (valid) {
        int iz = rc / EXT_XM, ix = rc - iz * EXT_XM;
        izv = iz; ixv = ix;
        int gz = z0 - HALO + iz; gz += (gz < 0) ? NZP : 0; gz -= (gz >= NZP) ? NZP : 0;
        int gx = x0 - HALO + ix; gx += (gx < 0) ? NXP : 0; gx -= (gx >= NXP) ? NXP : 0;
        g = gz * NXP + gx;
        cb    = coeff[0 * NCELL + g];
        cd    = coeff[1 * NCELL + g];
        cca   = coeff[2 * NCELL + g];
        ccl   = coeff[3 * NCELL + g];
        cdtcm = coeff[4 * NCELL + g];
        int liz = iz - HALO, lix = ix - HALO;
        inter = (liz >= 0 && liz < tzb && lix >= 0 && lix < TXB);
        int gzi = z0 + liz, gxi = x0 + lix;
        seis = (inter && gzi == NPADC + 1 && gxi >= NPADC && gxi < NPADC + NXI)
                   ? (gxi - NPADC) : -1;
        // owner block of this (halo) cell, by tile geometry
        int zbo = (gz < 66) ? gz / 11 : 6 + (gz - 66) / 10;
        int xbo = gx / TXB;
        ownerflag = (zbo * NXB + xbo) * FLAGSTRIDE;
    }
    // source cell local index (injective: ez<=31<NZP, EXT_XM=30<NXP)
    int lzs = isz - (z0 - HALO); lzs = ((lzs % NZP) + NZP) % NZP;
    int lxs = isx - (x0 - HALO); lxs = ((lxs % NXP) + NXP) % NXP;
    const int src_rc = (lzs < ez && lxs < EXT_XM) ? lzs * EXT_XM + lxs : -1;

    float ilacc = 0.0f;   // per-thread illum accumulator (interior cells only)
    float rvx = 0.f, rvz = 0.f, rtxx = 0.f, rtzz = 0.f, rtxz = 0.f;

    // ---- time loop: K-step trapezoid chunks, owner-direct halo sync ----
    int t0 = 0, parity = 0;
    unsigned chunk = 0;
    while (t0 < nt) {
        const int ks = (nt - t0 >= KSTEPS) ? KSTEPS : (nt - t0);
        const bool last = (t0 + ks >= nt);
        float* srcb = parity ? buf1 : buf0;
        float* dstb = last ? fields_out : (parity ? buf0 : buf1);

        // halo threads: wait for own cell's owner block, then load.
        // interior threads: regs + LDS already hold current state (chunk>0).
        if (valid && (chunk == 0 || !inter)) {
            if (chunk > 0) {
                while (__hip_atomic_load(&flags[ownerflag], __ATOMIC_RELAXED,
                                         AGENT) < chunk)
                    __builtin_amdgcn_s_sleep(1);
            }
            rvx  = aload(&srcb[0 * NCELL + g]);
            rvz  = aload(&srcb[1 * NCELL + g]);
            rtxx = aload(&srcb[2 * NCELL + g]);
            rtzz = aload(&srcb[3 * NCELL + g]);
            rtxz = aload(&srcb[4 * NCELL + g]);
            lds[0][rc] = rvx;
            lds[1][rc] = rvz;
            lds[2][rc] = rtxx;
            lds[3][rc] = rtzz;
            lds[4][rc] = rtxz;
        }
        __syncthreads();

        for (int k = 1; k <= ks; ++k) {
            const int t = t0 + k - 1;
            {   // velocity phase (p = 2k-1)
                const int p = 2 * k - 1;
                if (izv >= p && izv < ez - p && ixv >= p && ixv < EXT_XM - p) {
                    float txx_p1 = lds[2][rc + 1];
                    float tzz_pE = lds[3][rc + EXT_XM];
                    float txz_mE = lds[4][rc - EXT_XM];
                    float txz_m1 = lds[4][rc - 1];
                    float t1 = txx_p1 - rtxx;
                    float t2 = rtxz - txz_mE;
                    float nvx = (rvx + cb * (t1 + t2)) * cd;
                    float t3 = tzz_pE - rtzz;
                    float t4 = rtxz - txz_m1;
                    float nvz = (rvz + cb * (t3 + t4)) * cd;
                    rvx = nvx; rvz = nvz;
                    lds[0][rc] = nvx;
                    lds[1][rc] = nvz;
                    if (seis >= 0) seismo[t * NXI + seis] = nvz;
                    // early store: interior vx/vz are FINAL after the last
                    // velocity phase (stress doesn't modify them) — their L3
                    // write latency overlaps the final stress phase
                    if (k == ks && inter) {
                        if (!last) {
                            astore(&dstb[0 * NCELL + g], nvx);
                            astore(&dstb[1 * NCELL + g], nvz);
                        } else {
                            fields_out[0 * NCELL + g] = nvx;
                            fields_out[1 * NCELL + g] = nvz;
                        }
                    }
                }
            }
            __syncthreads();
            {   // stress phase (p = 2k)
                const int p = 2 * k;
                if (izv >= p && izv < ez - p && ixv >= p && ixv < EXT_XM - p) {
                    float vx_m1 = lds[0][rc - 1];
                    float vz_mE = lds[1][rc - EXT_XM];
                    float vx_pE = lds[0][rc + EXT_XM];
                    float vz_p1 = lds[1][rc + 1];
                    float exx = rvx - vx_m1;
                    float ezz = rvz - vz_mE;
                    float e1 = cca * exx;
                    float e2 = ccl * ezz;
                    float ntxx = (rtxx + dtx * (e1 + e2)) * cd;
                    float e3 = ccl * exx;
                    float e4 = cca * ezz;
                    float ntzz = (rtzz + dtx * (e3 + e4)) * cd;
                    float p1 = vx_pE - rvx;
                    float p2 = vz_p1 - rvz;
                    float ntxz = (rtxz + cdtcm * (p1 + p2)) * cd;
                    if (rc == src_rc) {
                        float sv = s[t] * dt;
                        ntxx += sv;
                        ntzz += sv;
                    }
                    rtxx = ntxx; rtzz = ntzz; rtxz = ntxz;
                    lds[2][rc] = ntxx;
                    lds[3][rc] = ntzz;
                    lds[4][rc] = ntxz;
                    if (inter) {
                        float divv = exx + ezz;
                        ilacc += divv * divv;
                    }
                }
            }
            if (k < ks) __syncthreads();
        }

        // store interior stress straight from registers (final-phase values);
        // vx/vz were already stored during the last velocity phase
        if (inter) {
            if (!last) {
                astore(&dstb[2 * NCELL + g], rtxx);
                astore(&dstb[3 * NCELL + g], rtzz);
                astore(&dstb[4 * NCELL + g], rtxz);
            } else {
                fields_out[2 * NCELL + g] = rtxx;
                fields_out[3 * NCELL + g] = rtzz;
                fields_out[4 * NCELL + g] = rtxz;
                illum_out[g] = ilacc;
            }
        }

        t0 += ks; parity ^= 1; ++chunk;

        if (!last) {
            // drain own stores (per wave), join, publish completion
            asm volatile("s_waitcnt vmcnt(0)" ::: "memory");
            __syncthreads();   // all waves' stores drained before publish
            if (tid == 0)
                __hip_atomic_store(&flags[bid * FLAGSTRIDE], chunk,
                                   __ATOMIC_RELAXED, AGENT);
        }
    }
}

extern "C" void kernel_launch(void* const* d_in, const int* in_sizes, int n_in,
                              void* d_out, int out_size, void* d_ws, size_t ws_size,
                              hipStream_t stream) {
    const float* vp   = (const float*)d_in[0];
    const float* vs   = (const float*)d_in[1];
    const float* den  = (const float*)d_in[2];
    const float* ivec = (const float*)d_in[3];
    const float* temp = (const float*)d_in[4];
    const float* s    = (const float*)d_in[5];
    const int*   isz  = (const int*)d_in[7];
    const int*   isx  = (const int*)d_in[8];
    int nt = in_sizes[5];

    float* out    = (float*)d_out;
    float* fields = out;                        // uu1: 5*NCELL
    float* seismo = out + 5 * NCELL;            // nt*NXI
    float* illum  = seismo + (size_t)nt * NXI;  // NCELL

    float* ws    = (float*)d_ws;
    float* coeff = ws;                 // 5*NCELL
    float* buf0  = ws + 5 * NCELL;     // 5*NCELL
    float* buf1  = ws + 10 * NCELL;    // 5*NCELL
    unsigned* flags = (unsigned*)(ws + 15 * NCELL);   // NBLOCKS*FLAGSTRIDE

    setup_kernel<<<(NCELL + 255) / 256, 256, 0, stream>>>(
        vp, vs, den, ivec, temp, coeff, buf0, flags);

    persist_kernel<<<NBLOCKS, NTHREADS, 0, stream>>>(
        coeff, buf0, buf1, ivec, s, isz, isx,
        fields, illum, seismo, flags, nt);
}

// Round 13
// 1276.948 us; speedup vs baseline: 1.0142x; 1.0142x over previous
//
#include <hip/hip_runtime.h>

#define NPADC 40
#define NZ 26
#define NXI 120            // interior nx (seismo width)
#define NZP 106
#define NXP 200
#define NCELL (NZP * NXP)

#define KSTEPS 5
#define HALO (2 * KSTEPS)          // 10
// z tiles: 6 of 11 + 4 of 10 (all >= HALO); x tiles: 20 of 10
#define NZB 10
#define NXB 20
#define NBLOCKS (NZB * NXB)        // 200
#define TXB 10                     // constant x tile size
#define EXT_XM (TXB + 2 * HALO)    // 30 (constant LDS row stride)
#define EZMAX (11 + 2 * HALO)      // 31
#define LDSN (EZMAX * EXT_XM)      // 930
#define NTHREADS 1024              // one thread per ext-tile cell
#define FLAGSTRIDE 32              // uints -> 128 B per flag line

#define AGENT __HIP_MEMORY_SCOPE_AGENT

__device__ __forceinline__ float aload(float* p) {
    return __hip_atomic_load(p, __ATOMIC_RELAXED, AGENT);
}
__device__ __forceinline__ void astore(float* p, float v) {
    __hip_atomic_store(p, v, __ATOMIC_RELAXED, AGENT);
}

// ---- damp profile, matching _damp_profile in fp32 ----
__device__ __forceinline__ float dprof(int idx, int n) {
#pragma clang fp contract(off)
    float fi = (float)idx;
    float left = 1.0f, right = 1.0f;
    if (idx < NPADC) {
        float a = 0.015f * ((float)NPADC - fi);
        left = expf(-(a * a));
    }
    if (idx >= n - NPADC) {
        float a = 0.015f * (fi - (float)(n - NPADC - 1));
        right = expf(-(a * a));
    }
    return left * right;
}

// ---- one-time setup: coefficients into ws, init state buf0, zero flags ----
__global__ void setup_kernel(const float* __restrict__ vp,
                             const float* __restrict__ vs,
                             const float* __restrict__ den,
                             const float* __restrict__ ivec,
                             const float* __restrict__ temp,
                             float* __restrict__ coeff,
                             float* __restrict__ buf0,
                             unsigned* __restrict__ flags) {
#pragma clang fp contract(off)
    int i = blockIdx.x * blockDim.x + threadIdx.x;
    if (i < NBLOCKS * FLAGSTRIDE) flags[i] = 0u;
    if (i >= NCELL) return;
    int z = i / NXP;
    int x = i - z * NXP;

    float dtx = ivec[3];

    int zi = z - NPADC; zi = zi < 0 ? 0 : (zi > NZ - 1 ? NZ - 1 : zi);
    int xi = x - NPADC; xi = xi < 0 ? 0 : (xi > NXI - 1 ? NXI - 1 : xi);
    float vpv = vp[zi * NXI + xi];
    float vsv = vs[zi * NXI + xi];
    float d = den[i];

    float cav = (vpv * vpv) * d;     // ca
    float cmv = (vsv * vsv) * d;     // cm
    coeff[0 * NCELL + i] = dtx / d;                        // b
    coeff[1 * NCELL + i] = dprof(z, NZP) * dprof(x, NXP);  // damp
    coeff[2 * NCELL + i] = cav;                            // ca
    coeff[3 * NCELL + i] = cav - 2.0f * cmv;               // cl
    coeff[4 * NCELL + i] = dtx * cmv;                      // dtx*cm

    for (int f = 0; f < 5; ++f)
        buf0[f * NCELL + i] = temp[f * NCELL + i];
}

// lds field order: 0=vx 1=vz 2=txx 3=tzz 4=txz
// Invariant: for threads inside the current active region, the registers
// rvx,rvz,rtxx,rtzz,rtxz mirror lds[f][rc] bit-exactly.
__global__ __launch_bounds__(NTHREADS)
void persist_kernel(const float* __restrict__ coeff,
                    float* __restrict__ buf0, float* __restrict__ buf1,
                    const float* __restrict__ ivec, const float* __restrict__ s,
                    const int* __restrict__ iszp, const int* __restrict__ isxp,
                    float* __restrict__ fields_out,
                    float* __restrict__ illum_out,
                    float* __restrict__ seismo,
                    unsigned* __restrict__ flags,
                    int nt) {
#pragma clang fp contract(off)
    __shared__ float lds[5][LDSN];

    const int tid = threadIdx.x;
    const int bid = blockIdx.x;
    const int zb = bid / NXB, xb = bid - zb * NXB;
    const int z0  = (zb < 6) ? 11 * zb : 66 + (zb - 6) * 10;
    const int tzb = (zb < 6) ? 11 : 10;
    const int x0  = xb * TXB;
    const int ez  = tzb + 2 * HALO;                      // 31 or 30
    const int ncl = ez * EXT_XM;
    const float dt  = ivec[2];
    const float dtx = ivec[3];
    const int isz = *iszp, isx = *isxp;

    // ---- per-thread cell precompute (one cell per thread) ----
    const int rc = tid;
    const bool valid = rc < ncl;
    int izv = -1000, ixv = -1000, g = 0, seis = -1, ownerflag = 0;
    bool inter = false;
    float cb = 0.f, cd = 0.f, cca = 0.f, ccl = 0.f, cdtcm = 0.f;
    if (valid) {
        int iz = rc / EXT_XM, ix = rc - iz * EXT_XM;
        izv = iz; ixv = ix;
        int gz = z0 - HALO + iz; gz += (gz < 0) ? NZP : 0; gz -= (gz >= NZP) ? NZP : 0;
        int gx = x0 - HALO + ix; gx += (gx < 0) ? NXP : 0; gx -= (gx >= NXP) ? NXP : 0;
        g = gz * NXP + gx;
        cb    = coeff[0 * NCELL + g];
        cd    = coeff[1 * NCELL + g];
        cca   = coeff[2 * NCELL + g];
        ccl   = coeff[3 * NCELL + g];
        cdtcm = coeff[4 * NCELL + g];
        int liz = iz - HALO, lix = ix - HALO;
        inter = (liz >= 0 && liz < tzb && lix >= 0 && lix < TXB);
        int gzi = z0 + liz, gxi = x0 + lix;
        seis = (inter && gzi == NPADC + 1 && gxi >= NPADC && gxi < NPADC + NXI)
                   ? (gxi - NPADC) : -1;
        // owner block of this (halo) cell, by tile geometry
        int zbo = (gz < 66) ? gz / 11 : 6 + (gz - 66) / 10;
        int xbo = gx / TXB;
        ownerflag = (zbo * NXB + xbo) * FLAGSTRIDE;
    }
    // source cell local index (injective: ez<=31<NZP, EXT_XM=30<NXP)
    int lzs = isz - (z0 - HALO); lzs = ((lzs % NZP) + NZP) % NZP;
    int lxs = isx - (x0 - HALO); lxs = ((lxs % NXP) + NXP) % NXP;
    const int src_rc = (lzs < ez && lxs < EXT_XM) ? lzs * EXT_XM + lxs : -1;

    float ilacc = 0.0f;   // per-thread illum accumulator (interior cells only)
    float rvx = 0.f, rvz = 0.f, rtxx = 0.f, rtzz = 0.f, rtxz = 0.f;

    // ---- time loop: K-step trapezoid chunks, owner-direct halo sync ----
    int t0 = 0, parity = 0;
    unsigned chunk = 0;
    while (t0 < nt) {
        const int ks = (nt - t0 >= KSTEPS) ? KSTEPS : (nt - t0);
        const bool last = (t0 + ks >= nt);
        float* srcb = parity ? buf1 : buf0;
        float* dstb = last ? fields_out : (parity ? buf0 : buf1);

        // halo threads: wait for own cell's owner block, then load.
        // interior threads: regs + LDS already hold current state (chunk>0).
        if (valid && (chunk == 0 || !inter)) {
            if (chunk > 0) {
                while (__hip_atomic_load(&flags[ownerflag], __ATOMIC_RELAXED,
                                         AGENT) < chunk)
                    __builtin_amdgcn_s_sleep(1);
            }
            rvx  = aload(&srcb[0 * NCELL + g]);
            rvz  = aload(&srcb[1 * NCELL + g]);
            rtxx = aload(&srcb[2 * NCELL + g]);
            rtzz = aload(&srcb[3 * NCELL + g]);
            rtxz = aload(&srcb[4 * NCELL + g]);
            lds[0][rc] = rvx;
            lds[1][rc] = rvz;
            lds[2][rc] = rtxx;
            lds[3][rc] = rtzz;
            lds[4][rc] = rtxz;
        }
        __syncthreads();

        for (int k = 1; k <= ks; ++k) {
            const int t = t0 + k - 1;
            {   // velocity phase (p = 2k-1)
                const int p = 2 * k - 1;
                if (izv >= p && izv < ez - p && ixv >= p && ixv < EXT_XM - p) {
                    float txx_p1 = lds[2][rc + 1];
                    float tzz_pE = lds[3][rc + EXT_XM];
                    float txz_mE = lds[4][rc - EXT_XM];
                    float txz_m1 = lds[4][rc - 1];
                    float t1 = txx_p1 - rtxx;
                    float t2 = rtxz - txz_mE;
                    float nvx = (rvx + cb * (t1 + t2)) * cd;
                    float t3 = tzz_pE - rtzz;
                    float t4 = rtxz - txz_m1;
                    float nvz = (rvz + cb * (t3 + t4)) * cd;
                    rvx = nvx; rvz = nvz;
                    lds[0][rc] = nvx;
                    lds[1][rc] = nvz;
                    if (seis >= 0) seismo[t * NXI + seis] = nvz;
                }
            }
            __syncthreads();
            {   // stress phase (p = 2k)
                const int p = 2 * k;
                if (izv >= p && izv < ez - p && ixv >= p && ixv < EXT_XM - p) {
                    float vx_m1 = lds[0][rc - 1];
                    float vz_mE = lds[1][rc - EXT_XM];
                    float vx_pE = lds[0][rc + EXT_XM];
                    float vz_p1 = lds[1][rc + 1];
                    float exx = rvx - vx_m1;
                    float ezz = rvz - vz_mE;
                    float e1 = cca * exx;
                    float e2 = ccl * ezz;
                    float ntxx = (rtxx + dtx * (e1 + e2)) * cd;
                    float e3 = ccl * exx;
                    float e4 = cca * ezz;
                    float ntzz = (rtzz + dtx * (e3 + e4)) * cd;
                    float p1 = vx_pE - rvx;
                    float p2 = vz_p1 - rvz;
                    float ntxz = (rtxz + cdtcm * (p1 + p2)) * cd;
                    if (rc == src_rc) {
                        float sv = s[t] * dt;
                        ntxx += sv;
                        ntzz += sv;
                    }
                    rtxx = ntxx; rtzz = ntzz; rtxz = ntxz;
                    lds[2][rc] = ntxx;
                    lds[3][rc] = ntzz;
                    lds[4][rc] = ntxz;
                    if (inter) {
                        float divv = exx + ezz;
                        ilacc += divv * divv;
                    }
                }
            }
            if (k < ks) __syncthreads();
        }

        // store interior straight from registers (final-phase values)
        if (inter) {
            if (!last) {
                astore(&dstb[0 * NCELL + g], rvx);
                astore(&dstb[1 * NCELL + g], rvz);
                astore(&dstb[2 * NCELL + g], rtxx);
                astore(&dstb[3 * NCELL + g], rtzz);
                astore(&dstb[4 * NCELL + g], rtxz);
            } else {
                fields_out[0 * NCELL + g] = rvx;
                fields_out[1 * NCELL + g] = rvz;
                fields_out[2 * NCELL + g] = rtxx;
                fields_out[3 * NCELL + g] = rtzz;
                fields_out[4 * NCELL + g] = rtxz;
                illum_out[g] = ilacc;
            }
        }

        t0 += ks; parity ^= 1; ++chunk;

        if (!last) {
            // drain own stores (per wave), join, publish completion
            asm volatile("s_waitcnt vmcnt(0)" ::: "memory");
            __syncthreads();   // all waves' stores drained before publish
            if (tid == 0)
                __hip_atomic_store(&flags[bid * FLAGSTRIDE], chunk,
                                   __ATOMIC_RELAXED, AGENT);
        }
    }
}

extern "C" void kernel_launch(void* const* d_in, const int* in_sizes, int n_in,
                              void* d_out, int out_size, void* d_ws, size_t ws_size,
                              hipStream_t stream) {
    const float* vp   = (const float*)d_in[0];
    const float* vs   = (const float*)d_in[1];
    const float* den  = (const float*)d_in[2];
    const float* ivec = (const float*)d_in[3];
    const float* temp = (const float*)d_in[4];
    const float* s    = (const float*)d_in[5];
    const int*   isz  = (const int*)d_in[7];
    const int*   isx  = (const int*)d_in[8];
    int nt = in_sizes[5];

    float* out    = (float*)d_out;
    float* fields = out;                        // uu1: 5*NCELL
    float* seismo = out + 5 * NCELL;            // nt*NXI
    float* illum  = seismo + (size_t)nt * NXI;  // NCELL

    float* ws    = (float*)d_ws;
    float* coeff = ws;                 // 5*NCELL
    float* buf0  = ws + 5 * NCELL;     // 5*NCELL
    float* buf1  = ws + 10 * NCELL;    // 5*NCELL
    unsigned* flags = (unsigned*)(ws + 15 * NCELL);   // NBLOCKS*FLAGSTRIDE

    setup_kernel<<<(NCELL + 255) / 256, 256, 0, stream>>>(
        vp, vs, den, ivec, temp, coeff, buf0, flags);

    persist_kernel<<<NBLOCKS, NTHREADS, 0, stream>>>(
        coeff, buf0, buf1, ivec, s, isz, isx,
        fields, illum, seismo, flags, nt);
}